// Round 3
// baseline (3808.926 us; speedup 1.0000x reference)
//
#include <hip/hip_runtime.h>

// AtomSelectionModel GNN. R3: all GEMMs moved to split-bf16 MFMA
// (A ~ Ah+Al, W ~ Wh+Wl in bf16; C = Ah*Wh + Ah*Wl + Al*Wh via
// v_mfma_f32_32x32x16_bf16 -> fp32-grade accuracy at MFMA rate).
// Weights pre-split+transposed once per call into [n][kv] bf16 planes.

#define V_N 262144
#define E_N 524288
#define N_G 8192
#define FV_D 64
#define H_D 128

// virtual concatenated K axis for the pre-split transposed weight planes:
// [0,384) W_emb | [384,576) W_mlp1 | 576 + l*256 + {0:W1[l], 128:W2[l]}
#define KV_TOT 1600
#define KV_EMB 0
#define KV_M1 384
#define KV_L0 576

typedef __attribute__((ext_vector_type(8))) short short8;
typedef __attribute__((ext_vector_type(16))) float f32x16;

__device__ __forceinline__ f32x16 mfma_bf(short8 a, short8 b, f32x16 c) {
  return __builtin_amdgcn_mfma_f32_32x32x16_bf16(a, b, c, 0, 0, 0);
}

__device__ __forceinline__ unsigned short bf_rne(float v) {
  unsigned int u = __float_as_uint(v);
  u += 0x7fffu + ((u >> 16) & 1u);
  return (unsigned short)(u >> 16);
}
__device__ __forceinline__ void split_bf16(float v, unsigned short& h,
                                           unsigned short& l) {
  h = bf_rne(v);
  l = bf_rne(v - __uint_as_float(((unsigned int)h) << 16));
}

__device__ __forceinline__ void load16(const float* p, float f[16]) {
  *(float4*)&f[0]  = *(const float4*)(p);
  *(float4*)&f[4]  = *(const float4*)(p + 4);
  *(float4*)&f[8]  = *(const float4*)(p + 8);
  *(float4*)&f[12] = *(const float4*)(p + 12);
}

// stage 16 consecutive fp32 (one row, 16 k) into split hi/lo LDS planes
__device__ __forceinline__ void stage16(const float f[16], unsigned short* ah,
                                        unsigned short* al, int base) {
  unsigned short hs[16], ls[16];
  #pragma unroll
  for (int i = 0; i < 16; ++i) split_bf16(f[i], hs[i], ls[i]);
  *(short8*)&ah[base]     = *(const short8*)&hs[0];
  *(short8*)&ah[base + 8] = *(const short8*)&hs[8];
  *(short8*)&al[base]     = *(const short8*)&ls[0];
  *(short8*)&al[base + 8] = *(const short8*)&ls[8];
}

// one 32-k chunk of MFMA work for one wave (32 rows x 128 cols)
__device__ __forceinline__ void mfma_chunk(const unsigned short* ah,
                                           const unsigned short* al,
                                           const unsigned short* bh,
                                           const unsigned short* bl,
                                           int wr0, int lr, int lh,
                                           f32x16 acc[4]) {
  #pragma unroll
  for (int s = 0; s < 2; ++s) {
    const int ka = s * 16 + lh * 8;
    const short8 a_h = *(const short8*)&ah[(wr0 + lr) * 32 + ka];
    const short8 a_l = *(const short8*)&al[(wr0 + lr) * 32 + ka];
    #pragma unroll
    for (int tl = 0; tl < 4; ++tl) {
      const short8 b_h = *(const short8*)&bh[(tl * 32 + lr) * 32 + ka];
      const short8 b_l = *(const short8*)&bl[(tl * 32 + lr) * 32 + ka];
      acc[tl] = mfma_bf(a_h, b_h, acc[tl]);
      acc[tl] = mfma_bf(a_h, b_l, acc[tl]);
      acc[tl] = mfma_bf(a_l, b_h, acc[tl]);
    }
  }
}

// ---- weight pre-split: wth/wtl[n][kv], kv = virtual concatenated K ---------
__global__ __launch_bounds__(256) void k_wsplit(
    const float* __restrict__ W_emb, const float* __restrict__ Wm1,
    const float* __restrict__ W1, const float* __restrict__ W2,
    unsigned short* __restrict__ wth, unsigned short* __restrict__ wtl)
{
  const int idx = blockIdx.x * 256 + threadIdx.x;   // 128*1600 total
  const int n = idx / KV_TOT;
  const int kv = idx - n * KV_TOT;
  const float* src;
  int k;
  if (kv < KV_M1) { src = W_emb; k = kv; }
  else if (kv < KV_L0) { src = Wm1; k = kv - KV_M1; }
  else {
    const int r = kv - KV_L0;
    const int l = r >> 8;
    const int w2sel = (r >> 7) & 1;
    k = r & 127;
    src = (w2sel ? W2 : W1) + (size_t)l * H_D * H_D;
  }
  const float v = src[(size_t)k * H_D + n];
  unsigned short h, lo;
  split_bf16(v, h, lo);
  wth[idx] = h;
  wtl[idx] = lo;
}

// ---------------- embed: x = relu([x_upd | Zc[g] | Zb[g]] @ W + b), K=384 ----
__global__ __launch_bounds__(256, 3) void k_embed(
    const float* __restrict__ x_upd, const float* __restrict__ Zc,
    const float* __restrict__ Zb, const int* __restrict__ n2g,
    const unsigned short* __restrict__ wth, const unsigned short* __restrict__ wtl,
    const float* __restrict__ bias, float* __restrict__ xout)
{
  __shared__ unsigned short ah[128 * 32], al[128 * 32];
  __shared__ unsigned short bh[128 * 32], bl[128 * 32];
  __shared__ int g_lds[128];
  const int t = threadIdx.x;
  const int row0 = blockIdx.x * 128;
  if (t < 128) g_lds[t] = n2g[row0 + t];
  const int lane = t & 63, w = t >> 6;
  const int lr = lane & 31, lh = lane >> 5;
  const int wr0 = w * 32;
  const int rs = t >> 1, kg = (t & 1) * 16;
  f32x16 acc[4];
  #pragma unroll
  for (int tl = 0; tl < 4; ++tl)
    #pragma unroll
    for (int e = 0; e < 16; ++e) acc[tl][e] = 0.f;
  __syncthreads();
  for (int kc = 0; kc < 12; ++kc) {
    const int kb = kc * 32;
    const float* src;
    if (kb < 128)      src = x_upd + (size_t)(row0 + rs) * H_D + kb;
    else if (kb < 256) src = Zc + (size_t)g_lds[rs] * H_D + (kb - 128);
    else               src = Zb + (size_t)g_lds[rs] * H_D + (kb - 256);
    float fv[16];
    load16(src + kg, fv);
    const int koff = rs * KV_TOT + KV_EMB + kb + kg;   // rs doubles as col n
    const short8 pbh0 = *(const short8*)&wth[koff];
    const short8 pbh1 = *(const short8*)&wth[koff + 8];
    const short8 pbl0 = *(const short8*)&wtl[koff];
    const short8 pbl1 = *(const short8*)&wtl[koff + 8];
    __syncthreads();
    stage16(fv, ah, al, rs * 32 + kg);
    *(short8*)&bh[rs * 32 + kg] = pbh0; *(short8*)&bh[rs * 32 + kg + 8] = pbh1;
    *(short8*)&bl[rs * 32 + kg] = pbl0; *(short8*)&bl[rs * 32 + kg + 8] = pbl1;
    __syncthreads();
    mfma_chunk(ah, al, bh, bl, wr0, lr, lh, acc);
  }
  const int grow0 = row0 + wr0;
  #pragma unroll
  for (int tl = 0; tl < 4; ++tl) {
    const int col = tl * 32 + lr;
    const float bb = bias[col];
    #pragma unroll
    for (int r = 0; r < 16; ++r) {
      const int row = (r & 3) + 8 * (r >> 2) + 4 * lh;
      xout[(size_t)(grow0 + row) * H_D + col] = fmaxf(acc[tl][r] + bb, 0.f);
    }
  }
}

// ---------------- layer GEMM1: h = relu((x+agg) @ W1 + b), K=128 ------------
__global__ __launch_bounds__(256, 3) void k_gemm_xa(
    const float* __restrict__ x, const float* __restrict__ agg,
    const unsigned short* __restrict__ wth, const unsigned short* __restrict__ wtl,
    int kvbase, const float* __restrict__ bias, float* __restrict__ hout)
{
  __shared__ unsigned short ah[128 * 32], al[128 * 32];
  __shared__ unsigned short bh[128 * 32], bl[128 * 32];
  const int t = threadIdx.x;
  const int row0 = blockIdx.x * 128;
  const int lane = t & 63, w = t >> 6;
  const int lr = lane & 31, lh = lane >> 5;
  const int wr0 = w * 32;
  const int rs = t >> 1, kg = (t & 1) * 16;
  f32x16 acc[4];
  #pragma unroll
  for (int tl = 0; tl < 4; ++tl)
    #pragma unroll
    for (int e = 0; e < 16; ++e) acc[tl][e] = 0.f;
  for (int kc = 0; kc < 4; ++kc) {
    const int kb = kc * 32;
    float fv[16], gv[16];
    load16(x   + (size_t)(row0 + rs) * H_D + kb + kg, fv);
    load16(agg + (size_t)(row0 + rs) * H_D + kb + kg, gv);
    #pragma unroll
    for (int i = 0; i < 16; ++i) fv[i] += gv[i];
    const int koff = rs * KV_TOT + kvbase + kb + kg;
    const short8 pbh0 = *(const short8*)&wth[koff];
    const short8 pbh1 = *(const short8*)&wth[koff + 8];
    const short8 pbl0 = *(const short8*)&wtl[koff];
    const short8 pbl1 = *(const short8*)&wtl[koff + 8];
    __syncthreads();
    stage16(fv, ah, al, rs * 32 + kg);
    *(short8*)&bh[rs * 32 + kg] = pbh0; *(short8*)&bh[rs * 32 + kg + 8] = pbh1;
    *(short8*)&bl[rs * 32 + kg] = pbl0; *(short8*)&bl[rs * 32 + kg + 8] = pbl1;
    __syncthreads();
    mfma_chunk(ah, al, bh, bl, wr0, lr, lh, acc);
  }
  const int grow0 = row0 + wr0;
  #pragma unroll
  for (int tl = 0; tl < 4; ++tl) {
    const int col = tl * 32 + lr;
    const float bb = bias[col];
    #pragma unroll
    for (int r = 0; r < 16; ++r) {
      const int row = (r & 3) + 8 * (r >> 2) + 4 * lh;
      hout[(size_t)(grow0 + row) * H_D + col] = fmaxf(acc[tl][r] + bb, 0.f);
    }
  }
}

// ---------------- layer GEMM2: x += relu(h @ W2 + b), K=128 -----------------
__global__ __launch_bounds__(256, 3) void k_gemm_res(
    const float* __restrict__ h,
    const unsigned short* __restrict__ wth, const unsigned short* __restrict__ wtl,
    int kvbase, const float* __restrict__ bias, float* __restrict__ x)
{
  __shared__ unsigned short ah[128 * 32], al[128 * 32];
  __shared__ unsigned short bh[128 * 32], bl[128 * 32];
  const int t = threadIdx.x;
  const int row0 = blockIdx.x * 128;
  const int lane = t & 63, w = t >> 6;
  const int lr = lane & 31, lh = lane >> 5;
  const int wr0 = w * 32;
  const int rs = t >> 1, kg = (t & 1) * 16;
  f32x16 acc[4];
  #pragma unroll
  for (int tl = 0; tl < 4; ++tl)
    #pragma unroll
    for (int e = 0; e < 16; ++e) acc[tl][e] = 0.f;
  for (int kc = 0; kc < 4; ++kc) {
    const int kb = kc * 32;
    float fv[16];
    load16(h + (size_t)(row0 + rs) * H_D + kb + kg, fv);
    const int koff = rs * KV_TOT + kvbase + kb + kg;
    const short8 pbh0 = *(const short8*)&wth[koff];
    const short8 pbh1 = *(const short8*)&wth[koff + 8];
    const short8 pbl0 = *(const short8*)&wtl[koff];
    const short8 pbl1 = *(const short8*)&wtl[koff + 8];
    __syncthreads();
    stage16(fv, ah, al, rs * 32 + kg);
    *(short8*)&bh[rs * 32 + kg] = pbh0; *(short8*)&bh[rs * 32 + kg + 8] = pbh1;
    *(short8*)&bl[rs * 32 + kg] = pbl0; *(short8*)&bl[rs * 32 + kg + 8] = pbl1;
    __syncthreads();
    mfma_chunk(ah, al, bh, bl, wr0, lr, lh, acc);
  }
  const int grow0 = row0 + wr0;
  #pragma unroll
  for (int tl = 0; tl < 4; ++tl) {
    const int col = tl * 32 + lr;
    const float bb = bias[col];
    #pragma unroll
    for (int r = 0; r < 16; ++r) {
      const int row = (r & 3) + 8 * (r >> 2) + 4 * lh;
      float* xp = x + (size_t)(grow0 + row) * H_D + col;
      *xp = *xp + fmaxf(acc[tl][r] + bb, 0.f);
    }
  }
}

// ---- head: logit = relu([x | x_inp]@Wm1+bm1)@Wm2+bm2, K=192 ----------------
__global__ __launch_bounds__(256, 3) void k_head(
    const float* __restrict__ x, const float* __restrict__ x_inp,
    const unsigned short* __restrict__ wth, const unsigned short* __restrict__ wtl,
    const float* __restrict__ bm1, const float* __restrict__ Wm2,
    const float* __restrict__ bm2, float* __restrict__ logit)
{
  __shared__ unsigned short ah[128 * 32], al[128 * 32];
  __shared__ unsigned short bh[128 * 32], bl[128 * 32];
  const int t = threadIdx.x;
  const int row0 = blockIdx.x * 128;
  const int lane = t & 63, w = t >> 6;
  const int lr = lane & 31, lh = lane >> 5;
  const int wr0 = w * 32;
  const int rs = t >> 1, kg = (t & 1) * 16;
  f32x16 acc[4];
  #pragma unroll
  for (int tl = 0; tl < 4; ++tl)
    #pragma unroll
    for (int e = 0; e < 16; ++e) acc[tl][e] = 0.f;
  for (int kc = 0; kc < 6; ++kc) {
    const int kb = kc * 32;
    const float* src = (kb < 128)
        ? x + (size_t)(row0 + rs) * H_D + kb
        : x_inp + (size_t)(row0 + rs) * FV_D + (kb - 128);
    float fv[16];
    load16(src + kg, fv);
    const int koff = rs * KV_TOT + KV_M1 + kb + kg;
    const short8 pbh0 = *(const short8*)&wth[koff];
    const short8 pbh1 = *(const short8*)&wth[koff + 8];
    const short8 pbl0 = *(const short8*)&wtl[koff];
    const short8 pbl1 = *(const short8*)&wtl[koff + 8];
    __syncthreads();
    stage16(fv, ah, al, rs * 32 + kg);
    *(short8*)&bh[rs * 32 + kg] = pbh0; *(short8*)&bh[rs * 32 + kg + 8] = pbh1;
    *(short8*)&bl[rs * 32 + kg] = pbl0; *(short8*)&bl[rs * 32 + kg + 8] = pbl1;
    __syncthreads();
    mfma_chunk(ah, al, bh, bl, wr0, lr, lh, acc);
  }
  float s[16];
  #pragma unroll
  for (int r = 0; r < 16; ++r) s[r] = 0.f;
  #pragma unroll
  for (int tl = 0; tl < 4; ++tl) {
    const int col = tl * 32 + lr;
    const float bb = bm1[col];
    const float ww = Wm2[col];
    #pragma unroll
    for (int r = 0; r < 16; ++r)
      s[r] += fmaxf(acc[tl][r] + bb, 0.f) * ww;
  }
  #pragma unroll
  for (int off = 1; off < 32; off <<= 1)
    #pragma unroll
    for (int r = 0; r < 16; ++r) s[r] += __shfl_xor(s[r], off);
  if (lr == 0) {
    const float bb = bm2[0];
    #pragma unroll
    for (int r = 0; r < 16; ++r) {
      const int row = (r & 3) + 8 * (r >> 2) + 4 * lh;
      logit[row0 + wr0 + row] = s[r] + bb;
    }
  }
}

// =================== CSR build (once per call) ==============================
__global__ __launch_bounds__(256) void k_hist(const int* __restrict__ eidx,
                                              int* __restrict__ deg)
{
  const int e = blockIdx.x * 256 + threadIdx.x;
  atomicAdd(&deg[eidx[E_N + e]], 1);
}

__global__ __launch_bounds__(256) void k_scan_local(const int* __restrict__ deg,
                                                    int* __restrict__ rp,
                                                    int* __restrict__ bsum)
{
  __shared__ int sc[256];
  const int t = threadIdx.x;
  const int base = blockIdx.x * 1024 + t * 4;
  const int4 d = *(const int4*)(deg + base);
  const int s4 = d.x + d.y + d.z + d.w;
  sc[t] = s4;
  __syncthreads();
  for (int off = 1; off < 256; off <<= 1) {
    int v = 0;
    if (t >= off) v = sc[t - off];
    __syncthreads();
    if (t >= off) sc[t] += v;
    __syncthreads();
  }
  const int excl = sc[t] - s4;
  int4 o;
  o.x = excl;
  o.y = excl + d.x;
  o.z = excl + d.x + d.y;
  o.w = excl + d.x + d.y + d.z;
  *(int4*)(rp + base) = o;
  if (t == 255) bsum[blockIdx.x] = sc[255];
}

__global__ __launch_bounds__(256) void k_scan_bsum(int* __restrict__ bsum)
{
  __shared__ int sc[256];
  const int t = threadIdx.x;
  const int b = bsum[t];
  sc[t] = b;
  __syncthreads();
  for (int off = 1; off < 256; off <<= 1) {
    int v = 0;
    if (t >= off) v = sc[t - off];
    __syncthreads();
    if (t >= off) sc[t] += v;
    __syncthreads();
  }
  bsum[t] = sc[t] - b;   // exclusive
}

__global__ __launch_bounds__(256) void k_scan_add(int* __restrict__ rp,
                                                  int* __restrict__ cursor,
                                                  const int* __restrict__ bsum)
{
  const int base = blockIdx.x * 1024 + threadIdx.x * 4;
  const int off = bsum[blockIdx.x];
  int4 r = *(const int4*)(rp + base);
  r.x += off; r.y += off; r.z += off; r.w += off;
  *(int4*)(rp + base) = r;
  *(int4*)(cursor + base) = r;
}

__global__ __launch_bounds__(256) void k_fill(const int* __restrict__ eidx,
                                              int* __restrict__ cursor,
                                              int* __restrict__ cs_src,
                                              int* __restrict__ cs_eid)
{
  const int e = blockIdx.x * 256 + threadIdx.x;
  const int d = eidx[E_N + e];
  const int p = atomicAdd(&cursor[d], 1);
  cs_src[p] = eidx[e];
  cs_eid[p] = e;
}

// ---- gather: agg[v] = sum_{e: dst=v} relu(x[src_e] + relu(attr_e@We+be)) ---
// 16 lanes x 8 cols per node, 16 nodes/block; We in LDS; no atomics.
__global__ __launch_bounds__(256, 4) void k_gather(
    const float* __restrict__ x, const float* __restrict__ attr,
    const int* __restrict__ rp, const int* __restrict__ deg,
    const int* __restrict__ cs_src, const int* __restrict__ cs_eid,
    const float* __restrict__ We, const float* __restrict__ be,
    float* __restrict__ agg)
{
  __shared__ float we_lds[16 * 128];
  const int t = threadIdx.x;
  {
    const int kk = t >> 4, c = (t & 15) * 8;
    *(float4*)&we_lds[kk * 128 + c]     = *(const float4*)(We + kk * H_D + c);
    *(float4*)&we_lds[kk * 128 + c + 4] = *(const float4*)(We + kk * H_D + c + 4);
  }
  __syncthreads();
  const int slot = t >> 4;
  const int c0 = (t & 15) * 8;
  const int v = blockIdx.x * 16 + slot;
  const int start = rp[v];
  const int n = deg[v];
  const float4 bev0 = *(const float4*)(be + c0);
  const float4 bev1 = *(const float4*)(be + c0 + 4);
  float4 acc0 = {0.f, 0.f, 0.f, 0.f};
  float4 acc1 = {0.f, 0.f, 0.f, 0.f};
  for (int i = 0; i < n; ++i) {
    const int p = start + i;
    const int s = cs_src[p];
    const int eid = cs_eid[p];
    const float* ap = attr + (size_t)eid * 16;
    float av[16];
    load16(ap, av);
    float4 e0 = bev0, e1 = bev1;
    #pragma unroll
    for (int k = 0; k < 16; ++k) {
      const float4 w0 = *(const float4*)&we_lds[k * 128 + c0];
      const float4 w1 = *(const float4*)&we_lds[k * 128 + c0 + 4];
      e0.x = fmaf(av[k], w0.x, e0.x); e0.y = fmaf(av[k], w0.y, e0.y);
      e0.z = fmaf(av[k], w0.z, e0.z); e0.w = fmaf(av[k], w0.w, e0.w);
      e1.x = fmaf(av[k], w1.x, e1.x); e1.y = fmaf(av[k], w1.y, e1.y);
      e1.z = fmaf(av[k], w1.z, e1.z); e1.w = fmaf(av[k], w1.w, e1.w);
    }
    const float4 xv0 = *(const float4*)(x + (size_t)s * H_D + c0);
    const float4 xv1 = *(const float4*)(x + (size_t)s * H_D + c0 + 4);
    acc0.x += fmaxf(xv0.x + fmaxf(e0.x, 0.f), 0.f);
    acc0.y += fmaxf(xv0.y + fmaxf(e0.y, 0.f), 0.f);
    acc0.z += fmaxf(xv0.z + fmaxf(e0.z, 0.f), 0.f);
    acc0.w += fmaxf(xv0.w + fmaxf(e0.w, 0.f), 0.f);
    acc1.x += fmaxf(xv1.x + fmaxf(e1.x, 0.f), 0.f);
    acc1.y += fmaxf(xv1.y + fmaxf(e1.y, 0.f), 0.f);
    acc1.z += fmaxf(xv1.z + fmaxf(e1.z, 0.f), 0.f);
    acc1.w += fmaxf(xv1.w + fmaxf(e1.w, 0.f), 0.f);
  }
  *(float4*)(agg + (size_t)v * H_D + c0) = acc0;
  *(float4*)(agg + (size_t)v * H_D + c0 + 4) = acc1;
}

// ---- segment softmax over sorted n2g: one wave per graph -------------------
__device__ __forceinline__ int lower_bound_i(const int* __restrict__ a, int n, int v)
{
  int lo = 0, hi = n;
  while (lo < hi) {
    const int mid = (lo + hi) >> 1;
    if (a[mid] < v) lo = mid + 1; else hi = mid;
  }
  return lo;
}

__global__ __launch_bounds__(256, 4) void k_softmax(
    const float* __restrict__ logit, const int* __restrict__ n2g,
    float* __restrict__ P)
{
  const int lane = threadIdx.x & 63;
  const int g = blockIdx.x * 4 + (threadIdx.x >> 6);
  const int s = lower_bound_i(n2g, V_N, g);
  const int e = lower_bound_i(n2g, V_N, g + 1);
  float m = -3.4e38f;
  for (int i = s + lane; i < e; i += 64) m = fmaxf(m, logit[i]);
  #pragma unroll
  for (int off = 32; off; off >>= 1) m = fmaxf(m, __shfl_xor(m, off));
  float sum = 0.f;
  for (int i = s + lane; i < e; i += 64) sum += __expf(logit[i] - m);
  #pragma unroll
  for (int off = 32; off; off >>= 1) sum += __shfl_xor(sum, off);
  const float inv = 1.f / sum;
  for (int i = s + lane; i < e; i += 64) P[i] = __expf(logit[i] - m) * inv;
}

extern "C" void kernel_launch(void* const* d_in, const int* in_sizes, int n_in,
                              void* d_out, int out_size, void* d_ws, size_t ws_size,
                              hipStream_t stream)
{
  const float* x_inp  = (const float*)d_in[0];
  const int*   eidx   = (const int*)  d_in[1];
  const float* attr   = (const float*)d_in[2];
  const float* x_upd  = (const float*)d_in[3];
  const float* Zc     = (const float*)d_in[4];
  const float* Zb     = (const float*)d_in[5];
  const int*   n2g    = (const int*)  d_in[6];
  const float* W_emb  = (const float*)d_in[7];
  const float* b_emb  = (const float*)d_in[8];
  const float* W_edge = (const float*)d_in[9];
  const float* b_edge = (const float*)d_in[10];
  const float* W1     = (const float*)d_in[11];
  const float* b1     = (const float*)d_in[12];
  const float* W2     = (const float*)d_in[13];
  const float* b2     = (const float*)d_in[14];
  const float* W_m1   = (const float*)d_in[15];
  const float* b_m1   = (const float*)d_in[16];
  const float* W_m2   = (const float*)d_in[17];
  const float* b_m2   = (const float*)d_in[18];

  float* ws     = (float*)d_ws;
  float* x      = ws;                               // V*H
  float* agg    = x + (size_t)V_N * H_D;            // V*H (reused as h)
  int*   deg    = (int*)(agg + (size_t)V_N * H_D);  // V
  int*   rp     = deg + V_N;                        // V
  int*   cursor = rp + V_N;                         // V (dead after k_fill)
  int*   cs_src = cursor + V_N;                     // E
  int*   cs_eid = cs_src + E_N;                     // E
  int*   bsum   = cs_eid + E_N;                     // 256
  unsigned short* wth = (unsigned short*)(bsum + 256);  // 128*1600
  unsigned short* wtl = wth + 128 * KV_TOT;             // 128*1600
  float* logit  = (float*)cursor;                   // V, aliases dead cursor

  // ---- weight split (tiny) + CSR by dst ----
  k_wsplit<<<128 * KV_TOT / 256, 256, 0, stream>>>(W_emb, W_m1, W1, W2, wth, wtl);
  hipMemsetAsync(deg, 0, (size_t)V_N * sizeof(int), stream);
  k_hist<<<E_N / 256, 256, 0, stream>>>(eidx, deg);
  k_scan_local<<<256, 256, 0, stream>>>(deg, rp, bsum);
  k_scan_bsum<<<1, 256, 0, stream>>>(bsum);
  k_scan_add<<<256, 256, 0, stream>>>(rp, cursor, bsum);
  k_fill<<<E_N / 256, 256, 0, stream>>>(eidx, cursor, cs_src, cs_eid);

  // ---- model ----
  k_embed<<<V_N / 128, 256, 0, stream>>>(x_upd, Zc, Zb, n2g, wth, wtl, b_emb, x);
  for (int l = 0; l < 4; ++l) {
    k_gather<<<V_N / 16, 256, 0, stream>>>(x, attr, rp, deg, cs_src, cs_eid,
                                           W_edge, b_edge, agg);
    k_gemm_xa<<<V_N / 128, 256, 0, stream>>>(x, agg, wth, wtl,
                                             KV_L0 + l * 256,
                                             b1 + (size_t)l * H_D, agg /* h */);
    k_gemm_res<<<V_N / 128, 256, 0, stream>>>(agg /* h */, wth, wtl,
                                              KV_L0 + l * 256 + 128,
                                              b2 + (size_t)l * H_D, x);
  }
  k_head<<<V_N / 128, 256, 0, stream>>>(x, x_inp, wth, wtl, b_m1, W_m2, b_m2,
                                        logit);
  k_softmax<<<N_G / 4, 256, 0, stream>>>(logit, n2g, (float*)d_out);
}

// Round 4
// 1662.638 us; speedup vs baseline: 2.2909x; 2.2909x over previous
//
#include <hip/hip_runtime.h>

// AtomSelectionModel GNN. R4: gather restructured —
//  (a) edge MLP relu(attr@We+be) precomputed ONCE per call into bf16,
//      stored in CSR order (streaming read in gather, was random + recomputed 4x)
//  (b) 32 lanes/node, edge loop unrolled x2, no LDS, all loads issued early.
// GEMMs stay split-bf16 MFMA (R3).

#define V_N 262144
#define E_N 524288
#define N_G 8192
#define FV_D 64
#define H_D 128

// virtual concatenated K axis for the pre-split transposed weight planes:
// [0,384) W_emb | [384,576) W_mlp1 | 576 + l*256 + {0:W1[l], 128:W2[l]}
#define KV_TOT 1600
#define KV_EMB 0
#define KV_M1 384
#define KV_L0 576

typedef __attribute__((ext_vector_type(8))) short short8;
typedef __attribute__((ext_vector_type(16))) float f32x16;

__device__ __forceinline__ f32x16 mfma_bf(short8 a, short8 b, f32x16 c) {
  return __builtin_amdgcn_mfma_f32_32x32x16_bf16(a, b, c, 0, 0, 0);
}

__device__ __forceinline__ unsigned short bf_rne(float v) {
  unsigned int u = __float_as_uint(v);
  u += 0x7fffu + ((u >> 16) & 1u);
  return (unsigned short)(u >> 16);
}
__device__ __forceinline__ void split_bf16(float v, unsigned short& h,
                                           unsigned short& l) {
  h = bf_rne(v);
  l = bf_rne(v - __uint_as_float(((unsigned int)h) << 16));
}

__device__ __forceinline__ void load16(const float* p, float f[16]) {
  *(float4*)&f[0]  = *(const float4*)(p);
  *(float4*)&f[4]  = *(const float4*)(p + 4);
  *(float4*)&f[8]  = *(const float4*)(p + 8);
  *(float4*)&f[12] = *(const float4*)(p + 12);
}

__device__ __forceinline__ float4 bf4_to_f4(uint2 u) {
  float4 r;
  r.x = __uint_as_float(u.x << 16);
  r.y = __uint_as_float(u.x & 0xffff0000u);
  r.z = __uint_as_float(u.y << 16);
  r.w = __uint_as_float(u.y & 0xffff0000u);
  return r;
}

// stage 16 consecutive fp32 (one row, 16 k) into split hi/lo LDS planes
__device__ __forceinline__ void stage16(const float f[16], unsigned short* ah,
                                        unsigned short* al, int base) {
  unsigned short hs[16], ls[16];
  #pragma unroll
  for (int i = 0; i < 16; ++i) split_bf16(f[i], hs[i], ls[i]);
  *(short8*)&ah[base]     = *(const short8*)&hs[0];
  *(short8*)&ah[base + 8] = *(const short8*)&hs[8];
  *(short8*)&al[base]     = *(const short8*)&ls[0];
  *(short8*)&al[base + 8] = *(const short8*)&ls[8];
}

// one 32-k chunk of MFMA work for one wave (32 rows x 128 cols)
__device__ __forceinline__ void mfma_chunk(const unsigned short* ah,
                                           const unsigned short* al,
                                           const unsigned short* bh,
                                           const unsigned short* bl,
                                           int wr0, int lr, int lh,
                                           f32x16 acc[4]) {
  #pragma unroll
  for (int s = 0; s < 2; ++s) {
    const int ka = s * 16 + lh * 8;
    const short8 a_h = *(const short8*)&ah[(wr0 + lr) * 32 + ka];
    const short8 a_l = *(const short8*)&al[(wr0 + lr) * 32 + ka];
    #pragma unroll
    for (int tl = 0; tl < 4; ++tl) {
      const short8 b_h = *(const short8*)&bh[(tl * 32 + lr) * 32 + ka];
      const short8 b_l = *(const short8*)&bl[(tl * 32 + lr) * 32 + ka];
      acc[tl] = mfma_bf(a_h, b_h, acc[tl]);
      acc[tl] = mfma_bf(a_h, b_l, acc[tl]);
      acc[tl] = mfma_bf(a_l, b_h, acc[tl]);
    }
  }
}

// ---- weight pre-split: wth/wtl[n][kv], kv = virtual concatenated K ---------
__global__ __launch_bounds__(256) void k_wsplit(
    const float* __restrict__ W_emb, const float* __restrict__ Wm1,
    const float* __restrict__ W1, const float* __restrict__ W2,
    unsigned short* __restrict__ wth, unsigned short* __restrict__ wtl)
{
  const int idx = blockIdx.x * 256 + threadIdx.x;   // 128*1600 total
  const int n = idx / KV_TOT;
  const int kv = idx - n * KV_TOT;
  const float* src;
  int k;
  if (kv < KV_M1) { src = W_emb; k = kv; }
  else if (kv < KV_L0) { src = Wm1; k = kv - KV_M1; }
  else {
    const int r = kv - KV_L0;
    const int l = r >> 8;
    const int w2sel = (r >> 7) & 1;
    k = r & 127;
    src = (w2sel ? W2 : W1) + (size_t)l * H_D * H_D;
  }
  const float v = src[(size_t)k * H_D + n];
  unsigned short h, lo;
  split_bf16(v, h, lo);
  wth[idx] = h;
  wtl[idx] = lo;
}

// ---------------- embed: x = relu([x_upd | Zc[g] | Zb[g]] @ W + b), K=384 ----
__global__ __launch_bounds__(256, 3) void k_embed(
    const float* __restrict__ x_upd, const float* __restrict__ Zc,
    const float* __restrict__ Zb, const int* __restrict__ n2g,
    const unsigned short* __restrict__ wth, const unsigned short* __restrict__ wtl,
    const float* __restrict__ bias, float* __restrict__ xout)
{
  __shared__ unsigned short ah[128 * 32], al[128 * 32];
  __shared__ unsigned short bh[128 * 32], bl[128 * 32];
  __shared__ int g_lds[128];
  const int t = threadIdx.x;
  const int row0 = blockIdx.x * 128;
  if (t < 128) g_lds[t] = n2g[row0 + t];
  const int lane = t & 63, w = t >> 6;
  const int lr = lane & 31, lh = lane >> 5;
  const int wr0 = w * 32;
  const int rs = t >> 1, kg = (t & 1) * 16;
  f32x16 acc[4];
  #pragma unroll
  for (int tl = 0; tl < 4; ++tl)
    #pragma unroll
    for (int e = 0; e < 16; ++e) acc[tl][e] = 0.f;
  __syncthreads();
  for (int kc = 0; kc < 12; ++kc) {
    const int kb = kc * 32;
    const float* src;
    if (kb < 128)      src = x_upd + (size_t)(row0 + rs) * H_D + kb;
    else if (kb < 256) src = Zc + (size_t)g_lds[rs] * H_D + (kb - 128);
    else               src = Zb + (size_t)g_lds[rs] * H_D + (kb - 256);
    float fv[16];
    load16(src + kg, fv);
    const int koff = rs * KV_TOT + KV_EMB + kb + kg;   // rs doubles as col n
    const short8 pbh0 = *(const short8*)&wth[koff];
    const short8 pbh1 = *(const short8*)&wth[koff + 8];
    const short8 pbl0 = *(const short8*)&wtl[koff];
    const short8 pbl1 = *(const short8*)&wtl[koff + 8];
    __syncthreads();
    stage16(fv, ah, al, rs * 32 + kg);
    *(short8*)&bh[rs * 32 + kg] = pbh0; *(short8*)&bh[rs * 32 + kg + 8] = pbh1;
    *(short8*)&bl[rs * 32 + kg] = pbl0; *(short8*)&bl[rs * 32 + kg + 8] = pbl1;
    __syncthreads();
    mfma_chunk(ah, al, bh, bl, wr0, lr, lh, acc);
  }
  const int grow0 = row0 + wr0;
  #pragma unroll
  for (int tl = 0; tl < 4; ++tl) {
    const int col = tl * 32 + lr;
    const float bb = bias[col];
    #pragma unroll
    for (int r = 0; r < 16; ++r) {
      const int row = (r & 3) + 8 * (r >> 2) + 4 * lh;
      xout[(size_t)(grow0 + row) * H_D + col] = fmaxf(acc[tl][r] + bb, 0.f);
    }
  }
}

// ---------------- layer GEMM1: h = relu((x+agg) @ W1 + b), K=128 ------------
__global__ __launch_bounds__(256, 3) void k_gemm_xa(
    const float* __restrict__ x, const float* __restrict__ agg,
    const unsigned short* __restrict__ wth, const unsigned short* __restrict__ wtl,
    int kvbase, const float* __restrict__ bias, float* __restrict__ hout)
{
  __shared__ unsigned short ah[128 * 32], al[128 * 32];
  __shared__ unsigned short bh[128 * 32], bl[128 * 32];
  const int t = threadIdx.x;
  const int row0 = blockIdx.x * 128;
  const int lane = t & 63, w = t >> 6;
  const int lr = lane & 31, lh = lane >> 5;
  const int wr0 = w * 32;
  const int rs = t >> 1, kg = (t & 1) * 16;
  f32x16 acc[4];
  #pragma unroll
  for (int tl = 0; tl < 4; ++tl)
    #pragma unroll
    for (int e = 0; e < 16; ++e) acc[tl][e] = 0.f;
  for (int kc = 0; kc < 4; ++kc) {
    const int kb = kc * 32;
    float fv[16], gv[16];
    load16(x   + (size_t)(row0 + rs) * H_D + kb + kg, fv);
    load16(agg + (size_t)(row0 + rs) * H_D + kb + kg, gv);
    #pragma unroll
    for (int i = 0; i < 16; ++i) fv[i] += gv[i];
    const int koff = rs * KV_TOT + kvbase + kb + kg;
    const short8 pbh0 = *(const short8*)&wth[koff];
    const short8 pbh1 = *(const short8*)&wth[koff + 8];
    const short8 pbl0 = *(const short8*)&wtl[koff];
    const short8 pbl1 = *(const short8*)&wtl[koff + 8];
    __syncthreads();
    stage16(fv, ah, al, rs * 32 + kg);
    *(short8*)&bh[rs * 32 + kg] = pbh0; *(short8*)&bh[rs * 32 + kg + 8] = pbh1;
    *(short8*)&bl[rs * 32 + kg] = pbl0; *(short8*)&bl[rs * 32 + kg + 8] = pbl1;
    __syncthreads();
    mfma_chunk(ah, al, bh, bl, wr0, lr, lh, acc);
  }
  const int grow0 = row0 + wr0;
  #pragma unroll
  for (int tl = 0; tl < 4; ++tl) {
    const int col = tl * 32 + lr;
    const float bb = bias[col];
    #pragma unroll
    for (int r = 0; r < 16; ++r) {
      const int row = (r & 3) + 8 * (r >> 2) + 4 * lh;
      hout[(size_t)(grow0 + row) * H_D + col] = fmaxf(acc[tl][r] + bb, 0.f);
    }
  }
}

// ---------------- layer GEMM2: x += relu(h @ W2 + b), K=128 -----------------
__global__ __launch_bounds__(256, 3) void k_gemm_res(
    const float* __restrict__ h,
    const unsigned short* __restrict__ wth, const unsigned short* __restrict__ wtl,
    int kvbase, const float* __restrict__ bias, float* __restrict__ x)
{
  __shared__ unsigned short ah[128 * 32], al[128 * 32];
  __shared__ unsigned short bh[128 * 32], bl[128 * 32];
  const int t = threadIdx.x;
  const int row0 = blockIdx.x * 128;
  const int lane = t & 63, w = t >> 6;
  const int lr = lane & 31, lh = lane >> 5;
  const int wr0 = w * 32;
  const int rs = t >> 1, kg = (t & 1) * 16;
  f32x16 acc[4];
  #pragma unroll
  for (int tl = 0; tl < 4; ++tl)
    #pragma unroll
    for (int e = 0; e < 16; ++e) acc[tl][e] = 0.f;
  for (int kc = 0; kc < 4; ++kc) {
    const int kb = kc * 32;
    float fv[16];
    load16(h + (size_t)(row0 + rs) * H_D + kb + kg, fv);
    const int koff = rs * KV_TOT + kvbase + kb + kg;
    const short8 pbh0 = *(const short8*)&wth[koff];
    const short8 pbh1 = *(const short8*)&wth[koff + 8];
    const short8 pbl0 = *(const short8*)&wtl[koff];
    const short8 pbl1 = *(const short8*)&wtl[koff + 8];
    __syncthreads();
    stage16(fv, ah, al, rs * 32 + kg);
    *(short8*)&bh[rs * 32 + kg] = pbh0; *(short8*)&bh[rs * 32 + kg + 8] = pbh1;
    *(short8*)&bl[rs * 32 + kg] = pbl0; *(short8*)&bl[rs * 32 + kg + 8] = pbl1;
    __syncthreads();
    mfma_chunk(ah, al, bh, bl, wr0, lr, lh, acc);
  }
  const int grow0 = row0 + wr0;
  #pragma unroll
  for (int tl = 0; tl < 4; ++tl) {
    const int col = tl * 32 + lr;
    const float bb = bias[col];
    #pragma unroll
    for (int r = 0; r < 16; ++r) {
      const int row = (r & 3) + 8 * (r >> 2) + 4 * lh;
      float* xp = x + (size_t)(grow0 + row) * H_D + col;
      *xp = *xp + fmaxf(acc[tl][r] + bb, 0.f);
    }
  }
}

// ---- head: logit = relu([x | x_inp]@Wm1+bm1)@Wm2+bm2, K=192 ----------------
__global__ __launch_bounds__(256, 3) void k_head(
    const float* __restrict__ x, const float* __restrict__ x_inp,
    const unsigned short* __restrict__ wth, const unsigned short* __restrict__ wtl,
    const float* __restrict__ bm1, const float* __restrict__ Wm2,
    const float* __restrict__ bm2, float* __restrict__ logit)
{
  __shared__ unsigned short ah[128 * 32], al[128 * 32];
  __shared__ unsigned short bh[128 * 32], bl[128 * 32];
  const int t = threadIdx.x;
  const int row0 = blockIdx.x * 128;
  const int lane = t & 63, w = t >> 6;
  const int lr = lane & 31, lh = lane >> 5;
  const int wr0 = w * 32;
  const int rs = t >> 1, kg = (t & 1) * 16;
  f32x16 acc[4];
  #pragma unroll
  for (int tl = 0; tl < 4; ++tl)
    #pragma unroll
    for (int e = 0; e < 16; ++e) acc[tl][e] = 0.f;
  for (int kc = 0; kc < 6; ++kc) {
    const int kb = kc * 32;
    const float* src = (kb < 128)
        ? x + (size_t)(row0 + rs) * H_D + kb
        : x_inp + (size_t)(row0 + rs) * FV_D + (kb - 128);
    float fv[16];
    load16(src + kg, fv);
    const int koff = rs * KV_TOT + KV_M1 + kb + kg;
    const short8 pbh0 = *(const short8*)&wth[koff];
    const short8 pbh1 = *(const short8*)&wth[koff + 8];
    const short8 pbl0 = *(const short8*)&wtl[koff];
    const short8 pbl1 = *(const short8*)&wtl[koff + 8];
    __syncthreads();
    stage16(fv, ah, al, rs * 32 + kg);
    *(short8*)&bh[rs * 32 + kg] = pbh0; *(short8*)&bh[rs * 32 + kg + 8] = pbh1;
    *(short8*)&bl[rs * 32 + kg] = pbl0; *(short8*)&bl[rs * 32 + kg + 8] = pbl1;
    __syncthreads();
    mfma_chunk(ah, al, bh, bl, wr0, lr, lh, acc);
  }
  float s[16];
  #pragma unroll
  for (int r = 0; r < 16; ++r) s[r] = 0.f;
  #pragma unroll
  for (int tl = 0; tl < 4; ++tl) {
    const int col = tl * 32 + lr;
    const float bb = bm1[col];
    const float ww = Wm2[col];
    #pragma unroll
    for (int r = 0; r < 16; ++r)
      s[r] += fmaxf(acc[tl][r] + bb, 0.f) * ww;
  }
  #pragma unroll
  for (int off = 1; off < 32; off <<= 1)
    #pragma unroll
    for (int r = 0; r < 16; ++r) s[r] += __shfl_xor(s[r], off);
  if (lr == 0) {
    const float bb = bm2[0];
    #pragma unroll
    for (int r = 0; r < 16; ++r) {
      const int row = (r & 3) + 8 * (r >> 2) + 4 * lh;
      logit[row0 + wr0 + row] = s[r] + bb;
    }
  }
}

// =================== CSR build (once per call) ==============================
__global__ __launch_bounds__(256) void k_hist(const int* __restrict__ eidx,
                                              int* __restrict__ deg)
{
  const int e = blockIdx.x * 256 + threadIdx.x;
  atomicAdd(&deg[eidx[E_N + e]], 1);
}

__global__ __launch_bounds__(256) void k_scan_local(const int* __restrict__ deg,
                                                    int* __restrict__ rp,
                                                    int* __restrict__ bsum)
{
  __shared__ int sc[256];
  const int t = threadIdx.x;
  const int base = blockIdx.x * 1024 + t * 4;
  const int4 d = *(const int4*)(deg + base);
  const int s4 = d.x + d.y + d.z + d.w;
  sc[t] = s4;
  __syncthreads();
  for (int off = 1; off < 256; off <<= 1) {
    int v = 0;
    if (t >= off) v = sc[t - off];
    __syncthreads();
    if (t >= off) sc[t] += v;
    __syncthreads();
  }
  const int excl = sc[t] - s4;
  int4 o;
  o.x = excl;
  o.y = excl + d.x;
  o.z = excl + d.x + d.y;
  o.w = excl + d.x + d.y + d.z;
  *(int4*)(rp + base) = o;
  if (t == 255) bsum[blockIdx.x] = sc[255];
}

__global__ __launch_bounds__(256) void k_scan_bsum(int* __restrict__ bsum)
{
  __shared__ int sc[256];
  const int t = threadIdx.x;
  const int b = bsum[t];
  sc[t] = b;
  __syncthreads();
  for (int off = 1; off < 256; off <<= 1) {
    int v = 0;
    if (t >= off) v = sc[t - off];
    __syncthreads();
    if (t >= off) sc[t] += v;
    __syncthreads();
  }
  bsum[t] = sc[t] - b;   // exclusive
}

__global__ __launch_bounds__(256) void k_scan_add(int* __restrict__ rp,
                                                  int* __restrict__ cursor,
                                                  const int* __restrict__ bsum)
{
  const int base = blockIdx.x * 1024 + threadIdx.x * 4;
  const int off = bsum[blockIdx.x];
  int4 r = *(const int4*)(rp + base);
  r.x += off; r.y += off; r.z += off; r.w += off;
  *(int4*)(rp + base) = r;
  *(int4*)(cursor + base) = r;
}

__global__ __launch_bounds__(256) void k_fill(const int* __restrict__ eidx,
                                              int* __restrict__ cursor,
                                              int* __restrict__ cs_src,
                                              int* __restrict__ cs_eid)
{
  const int e = blockIdx.x * 256 + threadIdx.x;
  const int d = eidx[E_N + e];
  const int p = atomicAdd(&cursor[d], 1);
  cs_src[p] = eidx[e];
  cs_eid[p] = e;
}

// ---- edge MLP, once per call: emlp[p] = relu(attr[cs_eid[p]]@We+be), bf16 --
// 32 lanes x 4 cols per CSR position, 8 positions/block; We in LDS.
__global__ __launch_bounds__(256, 4) void k_emlp(
    const float* __restrict__ attr, const int* __restrict__ cs_eid,
    const float* __restrict__ We, const float* __restrict__ be,
    unsigned short* __restrict__ emlp)
{
  __shared__ float we_lds[16 * 128];
  const int t = threadIdx.x;
  {
    const int kk = t >> 4, c = (t & 15) * 8;
    *(float4*)&we_lds[kk * 128 + c]     = *(const float4*)(We + kk * H_D + c);
    *(float4*)&we_lds[kk * 128 + c + 4] = *(const float4*)(We + kk * H_D + c + 4);
  }
  __syncthreads();
  const int slot = t >> 5;
  const int c0 = (t & 31) * 4;
  const int p = blockIdx.x * 8 + slot;
  const int eid = cs_eid[p];
  const float* ap = attr + (size_t)eid * 16;
  float av[16];
  load16(ap, av);
  float4 ev = *(const float4*)(be + c0);
  #pragma unroll
  for (int k = 0; k < 16; ++k) {
    const float4 w = *(const float4*)&we_lds[k * 128 + c0];
    ev.x = fmaf(av[k], w.x, ev.x);
    ev.y = fmaf(av[k], w.y, ev.y);
    ev.z = fmaf(av[k], w.z, ev.z);
    ev.w = fmaf(av[k], w.w, ev.w);
  }
  uint2 pk;
  pk.x = (unsigned int)bf_rne(fmaxf(ev.x, 0.f)) |
         ((unsigned int)bf_rne(fmaxf(ev.y, 0.f)) << 16);
  pk.y = (unsigned int)bf_rne(fmaxf(ev.z, 0.f)) |
         ((unsigned int)bf_rne(fmaxf(ev.w, 0.f)) << 16);
  *(uint2*)&emlp[(size_t)p * H_D + c0] = pk;
}

// ---- gather: agg[v] = sum_{p in [rp[v],rp[v]+deg[v])} relu(x[cs_src[p]] + emlp[p])
// 32 lanes x 4 cols per node, 8 nodes/block, edge loop unrolled x2, no LDS.
__global__ __launch_bounds__(256, 8) void k_gather(
    const float* __restrict__ x, const unsigned short* __restrict__ emlp,
    const int* __restrict__ rp, const int* __restrict__ deg,
    const int* __restrict__ cs_src, float* __restrict__ agg)
{
  const int t = threadIdx.x;
  const int slot = t >> 5;
  const int c0 = (t & 31) * 4;
  const int v = blockIdx.x * 8 + slot;
  const int start = rp[v];
  const int n = deg[v];
  float4 acc = {0.f, 0.f, 0.f, 0.f};
  int i = 0;
  for (; i + 2 <= n; i += 2) {
    const int p = start + i;
    const int s0 = cs_src[p];
    const int s1 = cs_src[p + 1];
    const uint2 eu0 = *(const uint2*)&emlp[(size_t)p * H_D + c0];
    const uint2 eu1 = *(const uint2*)&emlp[(size_t)(p + 1) * H_D + c0];
    const float4 x0 = *(const float4*)(x + (size_t)s0 * H_D + c0);
    const float4 x1 = *(const float4*)(x + (size_t)s1 * H_D + c0);
    const float4 e0 = bf4_to_f4(eu0);
    const float4 e1 = bf4_to_f4(eu1);
    acc.x += fmaxf(x0.x + e0.x, 0.f) + fmaxf(x1.x + e1.x, 0.f);
    acc.y += fmaxf(x0.y + e0.y, 0.f) + fmaxf(x1.y + e1.y, 0.f);
    acc.z += fmaxf(x0.z + e0.z, 0.f) + fmaxf(x1.z + e1.z, 0.f);
    acc.w += fmaxf(x0.w + e0.w, 0.f) + fmaxf(x1.w + e1.w, 0.f);
  }
  if (i < n) {
    const int p = start + i;
    const int s0 = cs_src[p];
    const uint2 eu0 = *(const uint2*)&emlp[(size_t)p * H_D + c0];
    const float4 x0 = *(const float4*)(x + (size_t)s0 * H_D + c0);
    const float4 e0 = bf4_to_f4(eu0);
    acc.x += fmaxf(x0.x + e0.x, 0.f);
    acc.y += fmaxf(x0.y + e0.y, 0.f);
    acc.z += fmaxf(x0.z + e0.z, 0.f);
    acc.w += fmaxf(x0.w + e0.w, 0.f);
  }
  *(float4*)(agg + (size_t)v * H_D + c0) = acc;
}

// ---- segment softmax over sorted n2g: one wave per graph -------------------
__device__ __forceinline__ int lower_bound_i(const int* __restrict__ a, int n, int v)
{
  int lo = 0, hi = n;
  while (lo < hi) {
    const int mid = (lo + hi) >> 1;
    if (a[mid] < v) lo = mid + 1; else hi = mid;
  }
  return lo;
}

__global__ __launch_bounds__(256, 4) void k_softmax(
    const float* __restrict__ logit, const int* __restrict__ n2g,
    float* __restrict__ P)
{
  const int lane = threadIdx.x & 63;
  const int g = blockIdx.x * 4 + (threadIdx.x >> 6);
  const int s = lower_bound_i(n2g, V_N, g);
  const int e = lower_bound_i(n2g, V_N, g + 1);
  float m = -3.4e38f;
  for (int i = s + lane; i < e; i += 64) m = fmaxf(m, logit[i]);
  #pragma unroll
  for (int off = 32; off; off >>= 1) m = fmaxf(m, __shfl_xor(m, off));
  float sum = 0.f;
  for (int i = s + lane; i < e; i += 64) sum += __expf(logit[i] - m);
  #pragma unroll
  for (int off = 32; off; off >>= 1) sum += __shfl_xor(sum, off);
  const float inv = 1.f / sum;
  for (int i = s + lane; i < e; i += 64) P[i] = __expf(logit[i] - m) * inv;
}

extern "C" void kernel_launch(void* const* d_in, const int* in_sizes, int n_in,
                              void* d_out, int out_size, void* d_ws, size_t ws_size,
                              hipStream_t stream)
{
  const float* x_inp  = (const float*)d_in[0];
  const int*   eidx   = (const int*)  d_in[1];
  const float* attr   = (const float*)d_in[2];
  const float* x_upd  = (const float*)d_in[3];
  const float* Zc     = (const float*)d_in[4];
  const float* Zb     = (const float*)d_in[5];
  const int*   n2g    = (const int*)  d_in[6];
  const float* W_emb  = (const float*)d_in[7];
  const float* b_emb  = (const float*)d_in[8];
  const float* W_edge = (const float*)d_in[9];
  const float* b_edge = (const float*)d_in[10];
  const float* W1     = (const float*)d_in[11];
  const float* b1     = (const float*)d_in[12];
  const float* W2     = (const float*)d_in[13];
  const float* b2     = (const float*)d_in[14];
  const float* W_m1   = (const float*)d_in[15];
  const float* b_m1   = (const float*)d_in[16];
  const float* W_m2   = (const float*)d_in[17];
  const float* b_m2   = (const float*)d_in[18];

  float* ws     = (float*)d_ws;
  float* x      = ws;                               // V*H f32
  float* agg    = x + (size_t)V_N * H_D;            // V*H f32 (reused as h)
  int*   deg    = (int*)(agg + (size_t)V_N * H_D);  // V
  int*   rp     = deg + V_N;                        // V
  int*   cursor = rp + V_N;                         // V (dead after k_fill)
  int*   cs_src = cursor + V_N;                     // E
  int*   cs_eid = cs_src + E_N;                     // E
  int*   bsum   = cs_eid + E_N;                     // 256
  unsigned short* wth  = (unsigned short*)(bsum + 256);  // 128*1600
  unsigned short* wtl  = wth + 128 * KV_TOT;             // 128*1600
  unsigned short* emlp = wtl + 128 * KV_TOT;             // E*128 bf16 (134 MB)
  float* logit  = (float*)cursor;                   // V, aliases dead cursor

  // ---- weight split + CSR by dst + edge-MLP precompute ----
  k_wsplit<<<128 * KV_TOT / 256, 256, 0, stream>>>(W_emb, W_m1, W1, W2, wth, wtl);
  hipMemsetAsync(deg, 0, (size_t)V_N * sizeof(int), stream);
  k_hist<<<E_N / 256, 256, 0, stream>>>(eidx, deg);
  k_scan_local<<<256, 256, 0, stream>>>(deg, rp, bsum);
  k_scan_bsum<<<1, 256, 0, stream>>>(bsum);
  k_scan_add<<<256, 256, 0, stream>>>(rp, cursor, bsum);
  k_fill<<<E_N / 256, 256, 0, stream>>>(eidx, cursor, cs_src, cs_eid);
  k_emlp<<<E_N / 8, 256, 0, stream>>>(attr, cs_eid, W_edge, b_edge, emlp);

  // ---- model ----
  k_embed<<<V_N / 128, 256, 0, stream>>>(x_upd, Zc, Zb, n2g, wth, wtl, b_emb, x);
  for (int l = 0; l < 4; ++l) {
    k_gather<<<V_N / 8, 256, 0, stream>>>(x, emlp, rp, deg, cs_src, agg);
    k_gemm_xa<<<V_N / 128, 256, 0, stream>>>(x, agg, wth, wtl,
                                             KV_L0 + l * 256,
                                             b1 + (size_t)l * H_D, agg /* h */);
    k_gemm_res<<<V_N / 128, 256, 0, stream>>>(agg /* h */, wth, wtl,
                                              KV_L0 + l * 256 + 128,
                                              b2 + (size_t)l * H_D, x);
  }
  k_head<<<V_N / 128, 256, 0, stream>>>(x, x_inp, wth, wtl, b_m1, W_m2, b_m2,
                                        logit);
  k_softmax<<<N_G / 4, 256, 0, stream>>>(logit, n2g, (float*)d_out);
}

// Round 5
// 1632.656 us; speedup vs baseline: 2.3330x; 1.0184x over previous
//
#include <hip/hip_runtime.h>

// AtomSelectionModel GNN. R5: LDS row stride 32->40 shorts (80 B = 20 banks)
// in all MFMA GEMMs — R4's 64-B stride gave ~16-way bank conflicts on
// ds_read_b128 (SQ_LDS_BANK_CONFLICT 3e7, MfmaUtil 23%); stride-40 gives
// uniform 8 words/bank = structural minimum.

#define V_N 262144
#define E_N 524288
#define N_G 8192
#define FV_D 64
#define H_D 128

#define LDSTR 40   // LDS row stride in shorts (80 B = 20 banks, 16-B aligned)

// virtual concatenated K axis for the pre-split transposed weight planes:
// [0,384) W_emb | [384,576) W_mlp1 | 576 + l*256 + {0:W1[l], 128:W2[l]}
#define KV_TOT 1600
#define KV_EMB 0
#define KV_M1 384
#define KV_L0 576

typedef __attribute__((ext_vector_type(8))) short short8;
typedef __attribute__((ext_vector_type(16))) float f32x16;

__device__ __forceinline__ f32x16 mfma_bf(short8 a, short8 b, f32x16 c) {
  return __builtin_amdgcn_mfma_f32_32x32x16_bf16(a, b, c, 0, 0, 0);
}

__device__ __forceinline__ unsigned short bf_rne(float v) {
  unsigned int u = __float_as_uint(v);
  u += 0x7fffu + ((u >> 16) & 1u);
  return (unsigned short)(u >> 16);
}
__device__ __forceinline__ void split_bf16(float v, unsigned short& h,
                                           unsigned short& l) {
  h = bf_rne(v);
  l = bf_rne(v - __uint_as_float(((unsigned int)h) << 16));
}

__device__ __forceinline__ void load16(const float* p, float f[16]) {
  *(float4*)&f[0]  = *(const float4*)(p);
  *(float4*)&f[4]  = *(const float4*)(p + 4);
  *(float4*)&f[8]  = *(const float4*)(p + 8);
  *(float4*)&f[12] = *(const float4*)(p + 12);
}

__device__ __forceinline__ float4 bf4_to_f4(uint2 u) {
  float4 r;
  r.x = __uint_as_float(u.x << 16);
  r.y = __uint_as_float(u.x & 0xffff0000u);
  r.z = __uint_as_float(u.y << 16);
  r.w = __uint_as_float(u.y & 0xffff0000u);
  return r;
}

// stage 16 consecutive fp32 (one row, 16 k) into split hi/lo LDS planes
__device__ __forceinline__ void stage16(const float f[16], unsigned short* ah,
                                        unsigned short* al, int base) {
  unsigned short hs[16], ls[16];
  #pragma unroll
  for (int i = 0; i < 16; ++i) split_bf16(f[i], hs[i], ls[i]);
  *(short8*)&ah[base]     = *(const short8*)&hs[0];
  *(short8*)&ah[base + 8] = *(const short8*)&hs[8];
  *(short8*)&al[base]     = *(const short8*)&ls[0];
  *(short8*)&al[base + 8] = *(const short8*)&ls[8];
}

// one 32-k chunk of MFMA work for one wave (32 rows x 128 cols)
__device__ __forceinline__ void mfma_chunk(const unsigned short* ah,
                                           const unsigned short* al,
                                           const unsigned short* bh,
                                           const unsigned short* bl,
                                           int wr0, int lr, int lh,
                                           f32x16 acc[4]) {
  #pragma unroll
  for (int s = 0; s < 2; ++s) {
    const int ka = s * 16 + lh * 8;
    const short8 a_h = *(const short8*)&ah[(wr0 + lr) * LDSTR + ka];
    const short8 a_l = *(const short8*)&al[(wr0 + lr) * LDSTR + ka];
    #pragma unroll
    for (int tl = 0; tl < 4; ++tl) {
      const short8 b_h = *(const short8*)&bh[(tl * 32 + lr) * LDSTR + ka];
      const short8 b_l = *(const short8*)&bl[(tl * 32 + lr) * LDSTR + ka];
      acc[tl] = mfma_bf(a_h, b_h, acc[tl]);
      acc[tl] = mfma_bf(a_h, b_l, acc[tl]);
      acc[tl] = mfma_bf(a_l, b_h, acc[tl]);
    }
  }
}

// ---- weight pre-split: wth/wtl[n][kv], kv = virtual concatenated K ---------
__global__ __launch_bounds__(256) void k_wsplit(
    const float* __restrict__ W_emb, const float* __restrict__ Wm1,
    const float* __restrict__ W1, const float* __restrict__ W2,
    unsigned short* __restrict__ wth, unsigned short* __restrict__ wtl)
{
  const int idx = blockIdx.x * 256 + threadIdx.x;   // 128*1600 total
  const int n = idx / KV_TOT;
  const int kv = idx - n * KV_TOT;
  const float* src;
  int k;
  if (kv < KV_M1) { src = W_emb; k = kv; }
  else if (kv < KV_L0) { src = Wm1; k = kv - KV_M1; }
  else {
    const int r = kv - KV_L0;
    const int l = r >> 8;
    const int w2sel = (r >> 7) & 1;
    k = r & 127;
    src = (w2sel ? W2 : W1) + (size_t)l * H_D * H_D;
  }
  const float v = src[(size_t)k * H_D + n];
  unsigned short h, lo;
  split_bf16(v, h, lo);
  wth[idx] = h;
  wtl[idx] = lo;
}

// ---------------- embed: x = relu([x_upd | Zc[g] | Zb[g]] @ W + b), K=384 ----
__global__ __launch_bounds__(256, 3) void k_embed(
    const float* __restrict__ x_upd, const float* __restrict__ Zc,
    const float* __restrict__ Zb, const int* __restrict__ n2g,
    const unsigned short* __restrict__ wth, const unsigned short* __restrict__ wtl,
    const float* __restrict__ bias, float* __restrict__ xout)
{
  __shared__ unsigned short ah[128 * LDSTR], al[128 * LDSTR];
  __shared__ unsigned short bh[128 * LDSTR], bl[128 * LDSTR];
  __shared__ int g_lds[128];
  const int t = threadIdx.x;
  const int row0 = blockIdx.x * 128;
  if (t < 128) g_lds[t] = n2g[row0 + t];
  const int lane = t & 63, w = t >> 6;
  const int lr = lane & 31, lh = lane >> 5;
  const int wr0 = w * 32;
  const int rs = t >> 1, kg = (t & 1) * 16;
  f32x16 acc[4];
  #pragma unroll
  for (int tl = 0; tl < 4; ++tl)
    #pragma unroll
    for (int e = 0; e < 16; ++e) acc[tl][e] = 0.f;
  __syncthreads();
  for (int kc = 0; kc < 12; ++kc) {
    const int kb = kc * 32;
    const float* src;
    if (kb < 128)      src = x_upd + (size_t)(row0 + rs) * H_D + kb;
    else if (kb < 256) src = Zc + (size_t)g_lds[rs] * H_D + (kb - 128);
    else               src = Zb + (size_t)g_lds[rs] * H_D + (kb - 256);
    float fv[16];
    load16(src + kg, fv);
    const int koff = rs * KV_TOT + KV_EMB + kb + kg;   // rs doubles as col n
    const short8 pbh0 = *(const short8*)&wth[koff];
    const short8 pbh1 = *(const short8*)&wth[koff + 8];
    const short8 pbl0 = *(const short8*)&wtl[koff];
    const short8 pbl1 = *(const short8*)&wtl[koff + 8];
    __syncthreads();
    stage16(fv, ah, al, rs * LDSTR + kg);
    *(short8*)&bh[rs * LDSTR + kg] = pbh0; *(short8*)&bh[rs * LDSTR + kg + 8] = pbh1;
    *(short8*)&bl[rs * LDSTR + kg] = pbl0; *(short8*)&bl[rs * LDSTR + kg + 8] = pbl1;
    __syncthreads();
    mfma_chunk(ah, al, bh, bl, wr0, lr, lh, acc);
  }
  const int grow0 = row0 + wr0;
  #pragma unroll
  for (int tl = 0; tl < 4; ++tl) {
    const int col = tl * 32 + lr;
    const float bb = bias[col];
    #pragma unroll
    for (int r = 0; r < 16; ++r) {
      const int row = (r & 3) + 8 * (r >> 2) + 4 * lh;
      xout[(size_t)(grow0 + row) * H_D + col] = fmaxf(acc[tl][r] + bb, 0.f);
    }
  }
}

// ---------------- layer GEMM1: h = relu((x+agg) @ W1 + b), K=128 ------------
__global__ __launch_bounds__(256, 3) void k_gemm_xa(
    const float* __restrict__ x, const float* __restrict__ agg,
    const unsigned short* __restrict__ wth, const unsigned short* __restrict__ wtl,
    int kvbase, const float* __restrict__ bias, float* __restrict__ hout)
{
  __shared__ unsigned short ah[128 * LDSTR], al[128 * LDSTR];
  __shared__ unsigned short bh[128 * LDSTR], bl[128 * LDSTR];
  const int t = threadIdx.x;
  const int row0 = blockIdx.x * 128;
  const int lane = t & 63, w = t >> 6;
  const int lr = lane & 31, lh = lane >> 5;
  const int wr0 = w * 32;
  const int rs = t >> 1, kg = (t & 1) * 16;
  f32x16 acc[4];
  #pragma unroll
  for (int tl = 0; tl < 4; ++tl)
    #pragma unroll
    for (int e = 0; e < 16; ++e) acc[tl][e] = 0.f;
  for (int kc = 0; kc < 4; ++kc) {
    const int kb = kc * 32;
    float fv[16], gv[16];
    load16(x   + (size_t)(row0 + rs) * H_D + kb + kg, fv);
    load16(agg + (size_t)(row0 + rs) * H_D + kb + kg, gv);
    #pragma unroll
    for (int i = 0; i < 16; ++i) fv[i] += gv[i];
    const int koff = rs * KV_TOT + kvbase + kb + kg;
    const short8 pbh0 = *(const short8*)&wth[koff];
    const short8 pbh1 = *(const short8*)&wth[koff + 8];
    const short8 pbl0 = *(const short8*)&wtl[koff];
    const short8 pbl1 = *(const short8*)&wtl[koff + 8];
    __syncthreads();
    stage16(fv, ah, al, rs * LDSTR + kg);
    *(short8*)&bh[rs * LDSTR + kg] = pbh0; *(short8*)&bh[rs * LDSTR + kg + 8] = pbh1;
    *(short8*)&bl[rs * LDSTR + kg] = pbl0; *(short8*)&bl[rs * LDSTR + kg + 8] = pbl1;
    __syncthreads();
    mfma_chunk(ah, al, bh, bl, wr0, lr, lh, acc);
  }
  const int grow0 = row0 + wr0;
  #pragma unroll
  for (int tl = 0; tl < 4; ++tl) {
    const int col = tl * 32 + lr;
    const float bb = bias[col];
    #pragma unroll
    for (int r = 0; r < 16; ++r) {
      const int row = (r & 3) + 8 * (r >> 2) + 4 * lh;
      hout[(size_t)(grow0 + row) * H_D + col] = fmaxf(acc[tl][r] + bb, 0.f);
    }
  }
}

// ---------------- layer GEMM2: x += relu(h @ W2 + b), K=128 -----------------
__global__ __launch_bounds__(256, 3) void k_gemm_res(
    const float* __restrict__ h,
    const unsigned short* __restrict__ wth, const unsigned short* __restrict__ wtl,
    int kvbase, const float* __restrict__ bias, float* __restrict__ x)
{
  __shared__ unsigned short ah[128 * LDSTR], al[128 * LDSTR];
  __shared__ unsigned short bh[128 * LDSTR], bl[128 * LDSTR];
  const int t = threadIdx.x;
  const int row0 = blockIdx.x * 128;
  const int lane = t & 63, w = t >> 6;
  const int lr = lane & 31, lh = lane >> 5;
  const int wr0 = w * 32;
  const int rs = t >> 1, kg = (t & 1) * 16;
  f32x16 acc[4];
  #pragma unroll
  for (int tl = 0; tl < 4; ++tl)
    #pragma unroll
    for (int e = 0; e < 16; ++e) acc[tl][e] = 0.f;
  for (int kc = 0; kc < 4; ++kc) {
    const int kb = kc * 32;
    float fv[16];
    load16(h + (size_t)(row0 + rs) * H_D + kb + kg, fv);
    const int koff = rs * KV_TOT + kvbase + kb + kg;
    const short8 pbh0 = *(const short8*)&wth[koff];
    const short8 pbh1 = *(const short8*)&wth[koff + 8];
    const short8 pbl0 = *(const short8*)&wtl[koff];
    const short8 pbl1 = *(const short8*)&wtl[koff + 8];
    __syncthreads();
    stage16(fv, ah, al, rs * LDSTR + kg);
    *(short8*)&bh[rs * LDSTR + kg] = pbh0; *(short8*)&bh[rs * LDSTR + kg + 8] = pbh1;
    *(short8*)&bl[rs * LDSTR + kg] = pbl0; *(short8*)&bl[rs * LDSTR + kg + 8] = pbl1;
    __syncthreads();
    mfma_chunk(ah, al, bh, bl, wr0, lr, lh, acc);
  }
  const int grow0 = row0 + wr0;
  #pragma unroll
  for (int tl = 0; tl < 4; ++tl) {
    const int col = tl * 32 + lr;
    const float bb = bias[col];
    #pragma unroll
    for (int r = 0; r < 16; ++r) {
      const int row = (r & 3) + 8 * (r >> 2) + 4 * lh;
      float* xp = x + (size_t)(grow0 + row) * H_D + col;
      *xp = *xp + fmaxf(acc[tl][r] + bb, 0.f);
    }
  }
}

// ---- head: logit = relu([x | x_inp]@Wm1+bm1)@Wm2+bm2, K=192 ----------------
__global__ __launch_bounds__(256, 3) void k_head(
    const float* __restrict__ x, const float* __restrict__ x_inp,
    const unsigned short* __restrict__ wth, const unsigned short* __restrict__ wtl,
    const float* __restrict__ bm1, const float* __restrict__ Wm2,
    const float* __restrict__ bm2, float* __restrict__ logit)
{
  __shared__ unsigned short ah[128 * LDSTR], al[128 * LDSTR];
  __shared__ unsigned short bh[128 * LDSTR], bl[128 * LDSTR];
  const int t = threadIdx.x;
  const int row0 = blockIdx.x * 128;
  const int lane = t & 63, w = t >> 6;
  const int lr = lane & 31, lh = lane >> 5;
  const int wr0 = w * 32;
  const int rs = t >> 1, kg = (t & 1) * 16;
  f32x16 acc[4];
  #pragma unroll
  for (int tl = 0; tl < 4; ++tl)
    #pragma unroll
    for (int e = 0; e < 16; ++e) acc[tl][e] = 0.f;
  for (int kc = 0; kc < 6; ++kc) {
    const int kb = kc * 32;
    const float* src = (kb < 128)
        ? x + (size_t)(row0 + rs) * H_D + kb
        : x_inp + (size_t)(row0 + rs) * FV_D + (kb - 128);
    float fv[16];
    load16(src + kg, fv);
    const int koff = rs * KV_TOT + KV_M1 + kb + kg;
    const short8 pbh0 = *(const short8*)&wth[koff];
    const short8 pbh1 = *(const short8*)&wth[koff + 8];
    const short8 pbl0 = *(const short8*)&wtl[koff];
    const short8 pbl1 = *(const short8*)&wtl[koff + 8];
    __syncthreads();
    stage16(fv, ah, al, rs * LDSTR + kg);
    *(short8*)&bh[rs * LDSTR + kg] = pbh0; *(short8*)&bh[rs * LDSTR + kg + 8] = pbh1;
    *(short8*)&bl[rs * LDSTR + kg] = pbl0; *(short8*)&bl[rs * LDSTR + kg + 8] = pbl1;
    __syncthreads();
    mfma_chunk(ah, al, bh, bl, wr0, lr, lh, acc);
  }
  float s[16];
  #pragma unroll
  for (int r = 0; r < 16; ++r) s[r] = 0.f;
  #pragma unroll
  for (int tl = 0; tl < 4; ++tl) {
    const int col = tl * 32 + lr;
    const float bb = bm1[col];
    const float ww = Wm2[col];
    #pragma unroll
    for (int r = 0; r < 16; ++r)
      s[r] += fmaxf(acc[tl][r] + bb, 0.f) * ww;
  }
  #pragma unroll
  for (int off = 1; off < 32; off <<= 1)
    #pragma unroll
    for (int r = 0; r < 16; ++r) s[r] += __shfl_xor(s[r], off);
  if (lr == 0) {
    const float bb = bm2[0];
    #pragma unroll
    for (int r = 0; r < 16; ++r) {
      const int row = (r & 3) + 8 * (r >> 2) + 4 * lh;
      logit[row0 + wr0 + row] = s[r] + bb;
    }
  }
}

// =================== CSR build (once per call) ==============================
__global__ __launch_bounds__(256) void k_hist(const int* __restrict__ eidx,
                                              int* __restrict__ deg)
{
  const int e = blockIdx.x * 256 + threadIdx.x;
  atomicAdd(&deg[eidx[E_N + e]], 1);
}

__global__ __launch_bounds__(256) void k_scan_local(const int* __restrict__ deg,
                                                    int* __restrict__ rp,
                                                    int* __restrict__ bsum)
{
  __shared__ int sc[256];
  const int t = threadIdx.x;
  const int base = blockIdx.x * 1024 + t * 4;
  const int4 d = *(const int4*)(deg + base);
  const int s4 = d.x + d.y + d.z + d.w;
  sc[t] = s4;
  __syncthreads();
  for (int off = 1; off < 256; off <<= 1) {
    int v = 0;
    if (t >= off) v = sc[t - off];
    __syncthreads();
    if (t >= off) sc[t] += v;
    __syncthreads();
  }
  const int excl = sc[t] - s4;
  int4 o;
  o.x = excl;
  o.y = excl + d.x;
  o.z = excl + d.x + d.y;
  o.w = excl + d.x + d.y + d.z;
  *(int4*)(rp + base) = o;
  if (t == 255) bsum[blockIdx.x] = sc[255];
}

__global__ __launch_bounds__(256) void k_scan_bsum(int* __restrict__ bsum)
{
  __shared__ int sc[256];
  const int t = threadIdx.x;
  const int b = bsum[t];
  sc[t] = b;
  __syncthreads();
  for (int off = 1; off < 256; off <<= 1) {
    int v = 0;
    if (t >= off) v = sc[t - off];
    __syncthreads();
    if (t >= off) sc[t] += v;
    __syncthreads();
  }
  bsum[t] = sc[t] - b;   // exclusive
}

__global__ __launch_bounds__(256) void k_scan_add(int* __restrict__ rp,
                                                  int* __restrict__ cursor,
                                                  const int* __restrict__ bsum)
{
  const int base = blockIdx.x * 1024 + threadIdx.x * 4;
  const int off = bsum[blockIdx.x];
  int4 r = *(const int4*)(rp + base);
  r.x += off; r.y += off; r.z += off; r.w += off;
  *(int4*)(rp + base) = r;
  *(int4*)(cursor + base) = r;
}

__global__ __launch_bounds__(256) void k_fill(const int* __restrict__ eidx,
                                              int* __restrict__ cursor,
                                              int* __restrict__ cs_src,
                                              int* __restrict__ cs_eid)
{
  const int e = blockIdx.x * 256 + threadIdx.x;
  const int d = eidx[E_N + e];
  const int p = atomicAdd(&cursor[d], 1);
  cs_src[p] = eidx[e];
  cs_eid[p] = e;
}

// ---- edge MLP, once per call: emlp[p] = relu(attr[cs_eid[p]]@We+be), bf16 --
__global__ __launch_bounds__(256, 4) void k_emlp(
    const float* __restrict__ attr, const int* __restrict__ cs_eid,
    const float* __restrict__ We, const float* __restrict__ be,
    unsigned short* __restrict__ emlp)
{
  __shared__ float we_lds[16 * 128];
  const int t = threadIdx.x;
  {
    const int kk = t >> 4, c = (t & 15) * 8;
    *(float4*)&we_lds[kk * 128 + c]     = *(const float4*)(We + kk * H_D + c);
    *(float4*)&we_lds[kk * 128 + c + 4] = *(const float4*)(We + kk * H_D + c + 4);
  }
  __syncthreads();
  const int slot = t >> 5;
  const int c0 = (t & 31) * 4;
  const int p = blockIdx.x * 8 + slot;
  const int eid = cs_eid[p];
  const float* ap = attr + (size_t)eid * 16;
  float av[16];
  load16(ap, av);
  float4 ev = *(const float4*)(be + c0);
  #pragma unroll
  for (int k = 0; k < 16; ++k) {
    const float4 w = *(const float4*)&we_lds[k * 128 + c0];
    ev.x = fmaf(av[k], w.x, ev.x);
    ev.y = fmaf(av[k], w.y, ev.y);
    ev.z = fmaf(av[k], w.z, ev.z);
    ev.w = fmaf(av[k], w.w, ev.w);
  }
  uint2 pk;
  pk.x = (unsigned int)bf_rne(fmaxf(ev.x, 0.f)) |
         ((unsigned int)bf_rne(fmaxf(ev.y, 0.f)) << 16);
  pk.y = (unsigned int)bf_rne(fmaxf(ev.z, 0.f)) |
         ((unsigned int)bf_rne(fmaxf(ev.w, 0.f)) << 16);
  *(uint2*)&emlp[(size_t)p * H_D + c0] = pk;
}

// ---- gather: agg[v] = sum_{p in [rp[v],rp[v]+deg[v])} relu(x[cs_src[p]] + emlp[p])
// 32 lanes x 4 cols per node, 8 nodes/block, edge loop unrolled x2, no LDS.
__global__ __launch_bounds__(256, 8) void k_gather(
    const float* __restrict__ x, const unsigned short* __restrict__ emlp,
    const int* __restrict__ rp, const int* __restrict__ deg,
    const int* __restrict__ cs_src, float* __restrict__ agg)
{
  const int t = threadIdx.x;
  const int slot = t >> 5;
  const int c0 = (t & 31) * 4;
  const int v = blockIdx.x * 8 + slot;
  const int start = rp[v];
  const int n = deg[v];
  float4 acc = {0.f, 0.f, 0.f, 0.f};
  int i = 0;
  for (; i + 2 <= n; i += 2) {
    const int p = start + i;
    const int s0 = cs_src[p];
    const int s1 = cs_src[p + 1];
    const uint2 eu0 = *(const uint2*)&emlp[(size_t)p * H_D + c0];
    const uint2 eu1 = *(const uint2*)&emlp[(size_t)(p + 1) * H_D + c0];
    const float4 x0 = *(const float4*)(x + (size_t)s0 * H_D + c0);
    const float4 x1 = *(const float4*)(x + (size_t)s1 * H_D + c0);
    const float4 e0 = bf4_to_f4(eu0);
    const float4 e1 = bf4_to_f4(eu1);
    acc.x += fmaxf(x0.x + e0.x, 0.f) + fmaxf(x1.x + e1.x, 0.f);
    acc.y += fmaxf(x0.y + e0.y, 0.f) + fmaxf(x1.y + e1.y, 0.f);
    acc.z += fmaxf(x0.z + e0.z, 0.f) + fmaxf(x1.z + e1.z, 0.f);
    acc.w += fmaxf(x0.w + e0.w, 0.f) + fmaxf(x1.w + e1.w, 0.f);
  }
  if (i < n) {
    const int p = start + i;
    const int s0 = cs_src[p];
    const uint2 eu0 = *(const uint2*)&emlp[(size_t)p * H_D + c0];
    const float4 x0 = *(const float4*)(x + (size_t)s0 * H_D + c0);
    const float4 e0 = bf4_to_f4(eu0);
    acc.x += fmaxf(x0.x + e0.x, 0.f);
    acc.y += fmaxf(x0.y + e0.y, 0.f);
    acc.z += fmaxf(x0.z + e0.z, 0.f);
    acc.w += fmaxf(x0.w + e0.w, 0.f);
  }
  *(float4*)(agg + (size_t)v * H_D + c0) = acc;
}

// ---- segment softmax over sorted n2g: one wave per graph -------------------
__device__ __forceinline__ int lower_bound_i(const int* __restrict__ a, int n, int v)
{
  int lo = 0, hi = n;
  while (lo < hi) {
    const int mid = (lo + hi) >> 1;
    if (a[mid] < v) lo = mid + 1; else hi = mid;
  }
  return lo;
}

__global__ __launch_bounds__(256, 4) void k_softmax(
    const float* __restrict__ logit, const int* __restrict__ n2g,
    float* __restrict__ P)
{
  const int lane = threadIdx.x & 63;
  const int g = blockIdx.x * 4 + (threadIdx.x >> 6);
  const int s = lower_bound_i(n2g, V_N, g);
  const int e = lower_bound_i(n2g, V_N, g + 1);
  float m = -3.4e38f;
  for (int i = s + lane; i < e; i += 64) m = fmaxf(m, logit[i]);
  #pragma unroll
  for (int off = 32; off; off >>= 1) m = fmaxf(m, __shfl_xor(m, off));
  float sum = 0.f;
  for (int i = s + lane; i < e; i += 64) sum += __expf(logit[i] - m);
  #pragma unroll
  for (int off = 32; off; off >>= 1) sum += __shfl_xor(sum, off);
  const float inv = 1.f / sum;
  for (int i = s + lane; i < e; i += 64) P[i] = __expf(logit[i] - m) * inv;
}

extern "C" void kernel_launch(void* const* d_in, const int* in_sizes, int n_in,
                              void* d_out, int out_size, void* d_ws, size_t ws_size,
                              hipStream_t stream)
{
  const float* x_inp  = (const float*)d_in[0];
  const int*   eidx   = (const int*)  d_in[1];
  const float* attr   = (const float*)d_in[2];
  const float* x_upd  = (const float*)d_in[3];
  const float* Zc     = (const float*)d_in[4];
  const float* Zb     = (const float*)d_in[5];
  const int*   n2g    = (const int*)  d_in[6];
  const float* W_emb  = (const float*)d_in[7];
  const float* b_emb  = (const float*)d_in[8];
  const float* W_edge = (const float*)d_in[9];
  const float* b_edge = (const float*)d_in[10];
  const float* W1     = (const float*)d_in[11];
  const float* b1     = (const float*)d_in[12];
  const float* W2     = (const float*)d_in[13];
  const float* b2     = (const float*)d_in[14];
  const float* W_m1   = (const float*)d_in[15];
  const float* b_m1   = (const float*)d_in[16];
  const float* W_m2   = (const float*)d_in[17];
  const float* b_m2   = (const float*)d_in[18];

  float* ws     = (float*)d_ws;
  float* x      = ws;                               // V*H f32
  float* agg    = x + (size_t)V_N * H_D;            // V*H f32 (reused as h)
  int*   deg    = (int*)(agg + (size_t)V_N * H_D);  // V
  int*   rp     = deg + V_N;                        // V
  int*   cursor = rp + V_N;                         // V (dead after k_fill)
  int*   cs_src = cursor + V_N;                     // E
  int*   cs_eid = cs_src + E_N;                     // E
  int*   bsum   = cs_eid + E_N;                     // 256
  unsigned short* wth  = (unsigned short*)(bsum + 256);  // 128*1600
  unsigned short* wtl  = wth + 128 * KV_TOT;             // 128*1600
  unsigned short* emlp = wtl + 128 * KV_TOT;             // E*128 bf16 (134 MB)
  float* logit  = (float*)cursor;                   // V, aliases dead cursor

  // ---- weight split + CSR by dst + edge-MLP precompute ----
  k_wsplit<<<128 * KV_TOT / 256, 256, 0, stream>>>(W_emb, W_m1, W1, W2, wth, wtl);
  hipMemsetAsync(deg, 0, (size_t)V_N * sizeof(int), stream);
  k_hist<<<E_N / 256, 256, 0, stream>>>(eidx, deg);
  k_scan_local<<<256, 256, 0, stream>>>(deg, rp, bsum);
  k_scan_bsum<<<1, 256, 0, stream>>>(bsum);
  k_scan_add<<<256, 256, 0, stream>>>(rp, cursor, bsum);
  k_fill<<<E_N / 256, 256, 0, stream>>>(eidx, cursor, cs_src, cs_eid);
  k_emlp<<<E_N / 8, 256, 0, stream>>>(attr, cs_eid, W_edge, b_edge, emlp);

  // ---- model ----
  k_embed<<<V_N / 128, 256, 0, stream>>>(x_upd, Zc, Zb, n2g, wth, wtl, b_emb, x);
  for (int l = 0; l < 4; ++l) {
    k_gather<<<V_N / 8, 256, 0, stream>>>(x, emlp, rp, deg, cs_src, agg);
    k_gemm_xa<<<V_N / 128, 256, 0, stream>>>(x, agg, wth, wtl,
                                             KV_L0 + l * 256,
                                             b1 + (size_t)l * H_D, agg /* h */);
    k_gemm_res<<<V_N / 128, 256, 0, stream>>>(agg /* h */, wth, wtl,
                                              KV_L0 + l * 256 + 128,
                                              b2 + (size_t)l * H_D, x);
  }
  k_head<<<V_N / 128, 256, 0, stream>>>(x, x_inp, wth, wtl, b_m1, W_m2, b_m2,
                                        logit);
  k_softmax<<<N_G / 4, 256, 0, stream>>>(logit, n2g, (float*)d_out);
}